// Round 15
// baseline (2437.922 us; speedup 1.0000x reference)
//
#include <hip/hip_runtime.h>
#include <hip/hip_fp16.h>
#include <cstdint>
#include <cstddef>

// Problem constants
#define B_   64
#define S_   512
#define F_   512
#define H_   1024
#define KTOT 1536
#define EPS_ 1e-3f
#define NBLK 256
#define NTHR 512

typedef _Float16 f16x8 __attribute__((ext_vector_type(8)));
typedef float    f32x4 __attribute__((ext_vector_type(4)));

// workspace layout (bytes)
#define WS_FLG_OFF  0                 // u32 flags[8 groups][32 blocks], 128B/line
#define WS_HBUF_OFF 4096              // fp16 h: [3][64][1024] = 384 KB
#define WS_WT_OFF   (1024*1024)       // fp16 [3*1024][1536] = 9 MB

#define MFMA16(A,Bf,C) __builtin_amdgcn_mfma_f32_16x16x32_f16(A, Bf, C, 0, 0, 0)

// ---------------- weight prep: fp16, transposed, [3*H][KTOT] ----------------
// Wt[(g*H + j)][k] = (k < H) ? W_g[k][j] : U_g[k-H][j]
__global__ void prep_weights(const float* __restrict__ Wr, const float* __restrict__ Wc,
                             const float* __restrict__ Wo, const float* __restrict__ Ur,
                             const float* __restrict__ Uc, const float* __restrict__ Uo,
                             _Float16* __restrict__ Wt) {
    int b  = blockIdx.x;            // 0..191
    int g  = b >> 6;                // gate 0..2
    int j0 = (b & 63) << 4;         // 16 columns per block
    const float* W = (g == 0) ? Wr : (g == 1) ? Wc : Wo;
    const float* U = (g == 0) ? Ur : (g == 1) ? Uc : Uo;
    int jj = threadIdx.x & 15;
    int kk = threadIdx.x >> 4;      // 0..15
    for (int k0 = 0; k0 < KTOT; k0 += 16) {
        int k = k0 + kk;
        float v = (k < H_) ? W[(size_t)k * H_ + j0 + jj]
                           : U[(size_t)(k - H_) * H_ + j0 + jj];
        Wt[(size_t)(g * H_ + j0 + jj) * KTOT + k] = (_Float16)v;
    }
}

// ---------------- persistent flag-sync recurrence kernel ----------------
// R14 structure with ONE change: PER-WAVE FLAG SUBSETS.
//   R14 post-mortem: R12 (atomic counter) == R14 (flag line) within noise ->
//   the dominant residual is straggler spread: each step gated on max over
//   32 producers. But consumer wave w consumes only h[128w..128w+128) =
//   output of 4 blocks (cg = 4w..4w+3). Now each wave polls ONLY its 4 flags
//   and immediately proceeds to its own h loads + h-MFMAs: max(4 jitters)
//   << max(32 jitters), and residual spread overlaps other waves' compute.
//   SAFETY unchanged: the block's publish still gates on all 32 flags
//   collectively (barrier #1 converges the 8 waves whose subsets cover all
//   32 blocks) -> triple-buffer skew proof carries over verbatim.
__global__ __launch_bounds__(NTHR, 2)
void plstm_flg(const float* __restrict__ x,
               const float* __restrict__ ts,
               const float* __restrict__ br,
               const float* __restrict__ bc,
               const float* __restrict__ bo,
               const _Float16* __restrict__ Wt,
               _Float16* __restrict__ hbuf,     // [3][64][1024] fp16
               unsigned* __restrict__ flags,    // [8][32] u32, 128B lines
               float* __restrict__ out) {
    __shared__ float    red[8 * 768];       // [wave][gate][8*32] = 24 KB
    __shared__ _Float16 hlog[64 * 256];     // 64-deep h log      = 32 KB

    const int tid = threadIdx.x;
    const int bid = blockIdx.x;
    const int grp = bid >> 5;            // batch-row group 0..7
    const int cg  = bid & 31;            // h-col group 0..31
    const int r0  = grp << 3;            // 8 rows
    const int c0  = cg << 5;             // 32 cols

    const int lane = tid & 63;
    const int w    = tid >> 6;           // wave 0..7
    const int arow = r0 + (lane & 7);    // A rows (M=8; lanes 8-15 duplicate)
    const int kblk = lane >> 4;          // 0..3
    const int jcol = lane & 15;          // B-fragment column within 16-col tile

    // ---- ALL weights into registers (AGPR-resident on gfx950) ----
    f16x8 bfh[3][2][4], bfx[3][2][2];
    #pragma unroll
    for (int g3 = 0; g3 < 3; ++g3)
        #pragma unroll
        for (int ct = 0; ct < 2; ++ct) {
            const _Float16* base = Wt + (size_t)(g3 * H_ + c0 + ct * 16 + jcol) * KTOT;
            #pragma unroll
            for (int sub = 0; sub < 4; ++sub)
                bfh[g3][ct][sub] = *(const f16x8*)(base + w * 128 + sub * 32 + kblk * 8);
            #pragma unroll
            for (int sub = 0; sub < 2; ++sub)
                bfx[g3][ct][sub] = *(const f16x8*)(base + H_ + w * 64 + sub * 32 + kblk * 8);
        }

    const int erow = tid >> 5;           // owner mapping (tid<256): 8 rows x 32 cols
    const int ecol = tid & 31;
    const int gb   = r0 + (erow & 7);
    const int gh   = c0 + ecol;
    float biasr = 0.f, biasc = 0.f, biaso = 0.f;
    if (tid < 256) { biasr = br[gh]; biasc = bc[gh]; biaso = bo[gh]; }
    float cst = 0.f, kst = 0.f, hval = 0.f;

    // per-wave producer subset: wave w consumes h cols [128w,+128) = blocks 4w..4w+3
    const unsigned* const fp = flags + grp * 32 + w * 4 + (lane & 3);
    unsigned* const myflag   = flags + grp * 32 + cg;           // this block's slot

    // ---- priming: x(0), ts(0) via plain loads (compiler-managed waits) ----
    f32x4 xn0, xn1, xn2, xn3; float tvn = 0.f;
    {
        const float* xp = x + (size_t)arow * S_ * F_ + w * 64 + kblk * 8;
        xn0 = *(const f32x4*)xp;        xn1 = *(const f32x4*)(xp + 4);
        xn2 = *(const f32x4*)(xp + 32); xn3 = *(const f32x4*)(xp + 36);
        if (tid < 256) tvn = ts[(size_t)gb * S_];
    }
    f16x8 xf0, xf1;
    #pragma unroll
    for (int r = 0; r < 4; ++r) { xf0[r] = (_Float16)xn0[r]; xf0[4 + r] = (_Float16)xn1[r]; }
    #pragma unroll
    for (int r = 0; r < 4; ++r) { xf1[r] = (_Float16)xn2[r]; xf1[4 + r] = (_Float16)xn3[r]; }
    float tv = tvn;

    for (int t = 0; t < S_; ++t) {
        // ---- x-part MFMAs (pure reg) overlap the flag round trip ----
        f32x4 acc[3][2] = {};
        #pragma unroll
        for (int g3 = 0; g3 < 3; ++g3)
            #pragma unroll
            for (int ct = 0; ct < 2; ++ct) {
                acc[g3][ct] = MFMA16(xf0, bfx[g3][ct][0], acc[g3][ct]);
                acc[g3][ct] = MFMA16(xf1, bfx[g3][ct][1], acc[g3][ct]);
            }

        // ---- detect: poll ONLY this wave's 4 producer flags ----
        if (t > 0) {
            const unsigned tgt = (unsigned)t;
            unsigned f;
            for (unsigned it = 0; it < (1u << 17); ++it) {
                asm volatile("global_load_dword %0, %1, off sc0 sc1\n\t"
                             "s_waitcnt vmcnt(0)"
                             : "=v"(f) : "v"(fp) : "memory");
                if (__all((int)(f >= tgt))) break;
            }
        }
        __builtin_amdgcn_sched_barrier(0);

        // ---- h data loads: this wave's 128 cols, fresh by its 4 flags ----
        const _Float16* hb = hbuf + (size_t)(t % 3) * B_ * H_
                                  + (size_t)arow * H_ + w * 128 + kblk * 8;
        f16x8 hfr[4];
        #pragma unroll
        for (int s = 0; s < 4; ++s)
            asm volatile("global_load_dwordx4 %0, %1, off sc0 sc1"
                         : "=v"(hfr[s]) : "v"(hb + s * 32));
        asm volatile("s_waitcnt vmcnt(0)" ::: "memory");
        __builtin_amdgcn_sched_barrier(0);

        // ---- prefetch x, ts for t+1 (plain loads, hidden under h-MFMAs) ----
        if (t + 1 < S_) {
            const float* xp = x + ((size_t)arow * S_ + (t + 1)) * F_ + w * 64 + kblk * 8;
            xn0 = *(const f32x4*)xp;        xn1 = *(const f32x4*)(xp + 4);
            xn2 = *(const f32x4*)(xp + 32); xn3 = *(const f32x4*)(xp + 36);
            if (tid < 256) tvn = ts[(size_t)gb * S_ + t + 1];
        }

        // ---- h-part MFMAs (pure reg) ----
        #pragma unroll
        for (int s = 0; s < 4; ++s)
            #pragma unroll
            for (int g3 = 0; g3 < 3; ++g3) {
                acc[g3][0] = MFMA16(hfr[s], bfh[g3][0][s], acc[g3][0]);
                acc[g3][1] = MFMA16(hfr[s], bfh[g3][1][s], acc[g3][1]);
            }

        // ---- cross-wave reduce: explicit per-wave slots ----
        if (lane < 32) {
            float* rw = red + w * 768;
            const int crow = (lane >> 4) << 2;
            const int ccol = lane & 15;
            #pragma unroll
            for (int i = 0; i < 4; ++i) {
                const int rr = (crow + i) * 32 + ccol;
                rw[rr]              = acc[0][0][i];  rw[rr + 16]         = acc[0][1][i];
                rw[256 + rr]        = acc[1][0][i];  rw[256 + rr + 16]   = acc[1][1][i];
                rw[512 + rr]        = acc[2][0][i];  rw[512 + rr + 16]   = acc[2][1][i];
            }
        }
        __syncthreads();   // barrier #1: red ready; ALL 32 flags collectively seen

        // ---- owners: sum partials ----
        float pr = biasr, pc = biasc, po = biaso;
        if (tid < 256) {
            #pragma unroll
            for (int ww = 0; ww < 8; ++ww) {
                pr += red[ww * 768 + tid];
                pc += red[ww * 768 + 256 + tid];
                po += red[ww * 768 + 512 + tid];
            }
        }

        if (tid < 256) {
            // ---- elementwise pLSTM update (f32) ----
            const float r = 1.f / (1.f + __expf(-pr));
            kst = r * tv + (1.f - r) * kst;
            const float e2 = __expf(2.f * pc);
            const float ctil = (e2 - 1.f) / (e2 + 1.f);
            const float d = tv - kst;
            const float f = __fsqrt_rn((d + EPS_) / (d + 1.f));  // ((d+1)/(d+eps))^-0.5
            cst = f * cst + (1.f - f) * ctil;
            const float o = 1.f / (1.f + __expf(-po));
            const float e2c = __expf(2.f * cst);
            hval = o * ((e2c - 1.f) / (e2c + 1.f));

            // publish plain fp16 h for t+1 (sc0sc1 -> LLC)
            if (t + 1 < S_) {
                union { _Float16 hf; unsigned short us; } cv; cv.hf = (_Float16)hval;
                unsigned short* hp = (unsigned short*)(hbuf
                    + (size_t)((t + 1) % 3) * B_ * H_ + (size_t)gb * H_ + gh);
                unsigned uv = cv.us;
                asm volatile("global_store_short %0, %1, off sc0 sc1"
                             :: "v"(hp), "v"(uv) : "memory");
            }
            hlog[(t & 63) * 256 + tid] = (_Float16)hval;
        }

        // ---- ACK publishes, then arrive: one plain store ----
        asm volatile("s_waitcnt vmcnt(0)" ::: "memory");  // owner stores ACKed in LLC
        __syncthreads();   // barrier #2: all owner publishes ACKed; red free
        if (tid == 0 && t + 1 < S_) {
            unsigned fv = (unsigned)(t + 1);
            asm volatile("global_store_dword %0, %1, off sc0 sc1"
                         :: "v"(myflag), "v"(fv) : "memory");
        }

        // ---- non-owners: burst-flush hlog every 32 steps (off critical path) ----
        if (tid >= 256 && (t & 31) == 0 && t) {
            const int tbase = t - 32;
            #pragma unroll
            for (int p = 0; p < 4; ++p) {
                const int m  = p * 256 + (tid - 256);  // 0..1023 chunks of 8 fp16
                const int dt = m >> 5;                 // 0..31
                const int c  = m & 31;                 // chunk within step
                f16x8 v = *(const f16x8*)(hlog + ((tbase + dt) & 63) * 256 + c * 8);
                float* op = out + ((size_t)(r0 + (c >> 2)) * S_ + tbase + dt) * H_
                                + c0 + (c & 3) * 8;
                f32x4 o0, o1;
                #pragma unroll
                for (int r2 = 0; r2 < 4; ++r2) { o0[r2] = (float)v[r2]; o1[r2] = (float)v[4 + r2]; }
                *(f32x4*)op = o0;
                *(f32x4*)(op + 4) = o1;
            }
        }

        // ---- tail: convert prefetched x ----
        if (t + 1 < S_) {
            #pragma unroll
            for (int r2 = 0; r2 < 4; ++r2) { xf0[r2] = (_Float16)xn0[r2]; xf0[4 + r2] = (_Float16)xn1[r2]; }
            #pragma unroll
            for (int r2 = 0; r2 < 4; ++r2) { xf1[r2] = (_Float16)xn2[r2]; xf1[4 + r2] = (_Float16)xn3[r2]; }
            tv = tvn;
        }
    }

    // ---- final flush of last 32 steps + final states ----
    __syncthreads();
    {
        const int tbase = S_ - 32;
        #pragma unroll
        for (int p = 0; p < 2; ++p) {
            const int m  = p * 512 + tid;
            const int dt = m >> 5;
            const int c  = m & 31;
            f16x8 v = *(const f16x8*)(hlog + ((tbase + dt) & 63) * 256 + c * 8);
            float* op = out + ((size_t)(r0 + (c >> 2)) * S_ + tbase + dt) * H_
                            + c0 + (c & 3) * 8;
            f32x4 o0, o1;
            #pragma unroll
            for (int r2 = 0; r2 < 4; ++r2) { o0[r2] = (float)v[r2]; o1[r2] = (float)v[4 + r2]; }
            *(f32x4*)op = o0;
            *(f32x4*)(op + 4) = o1;
        }
    }
    if (tid < 256) {
        const size_t BSH = (size_t)B_ * S_ * H_;
        out[BSH +                       (size_t)gb * H_ + gh] = hval;  // h_T
        out[BSH + (size_t)B_ * H_ +     (size_t)gb * H_ + gh] = cst;   // c_T
        out[BSH + 2 * (size_t)B_ * H_ + (size_t)gb * H_ + gh] = kst;   // k_T
    }
}

extern "C" void kernel_launch(void* const* d_in, const int* in_sizes, int n_in,
                              void* d_out, int out_size, void* d_ws, size_t ws_size,
                              hipStream_t stream) {
    (void)in_sizes; (void)n_in; (void)out_size; (void)ws_size;
    const float* x  = (const float*)d_in[0];
    const float* ts = (const float*)d_in[1];
    const float* Ur = (const float*)d_in[2];
    const float* Wr = (const float*)d_in[3];
    const float* br = (const float*)d_in[4];
    const float* Uc = (const float*)d_in[5];
    const float* Wc = (const float*)d_in[6];
    const float* bc = (const float*)d_in[7];
    const float* Uo = (const float*)d_in[8];
    const float* Wo = (const float*)d_in[9];
    const float* bo = (const float*)d_in[10];
    float* out = (float*)d_out;

    char* ws = (char*)d_ws;
    unsigned*  flags = (unsigned*)(ws + WS_FLG_OFF);
    _Float16*  hbuf  = (_Float16*)(ws + WS_HBUF_OFF);
    _Float16*  Wt    = (_Float16*)(ws + WS_WT_OFF);

    // zero flags + ALL h slots every launch (monotone flags must restart at 0
    // for graph replay; h slot 0 zero = valid h_0).
    hipMemsetAsync(ws, 0, WS_HBUF_OFF + 3 * B_ * H_ * 2, stream);

    prep_weights<<<192, 256, 0, stream>>>(Wr, Wc, Wo, Ur, Uc, Uo, Wt);

    plstm_flg<<<NBLK, NTHR, 0, stream>>>(x, ts, br, bc, bo, Wt, hbuf, flags, out);
}

// Round 16
// 1812.748 us; speedup vs baseline: 1.3449x; 1.3449x over previous
//
#include <hip/hip_runtime.h>
#include <hip/hip_fp16.h>
#include <cstdint>
#include <cstddef>

// Problem constants
#define B_   64
#define S_   512
#define F_   512
#define H_   1024
#define KTOT 1536
#define EPS_ 1e-3f
#define NBLK 256
#define NTHR 512

typedef _Float16 f16x8 __attribute__((ext_vector_type(8)));
typedef float    f32x4 __attribute__((ext_vector_type(4)));

// workspace layout (bytes)
#define WS_CNT_OFF  0                 // u32 counter per group, 128B-padded: 8*128 = 1 KB
#define WS_HBUF_OFF 4096              // fp16 h: [3][64][1024] = 384 KB
#define WS_WT_OFF   (1024*1024)       // fp16 [3*1024][1536] = 9 MB

#define MFMA16(A,Bf,C) __builtin_amdgcn_mfma_f32_16x16x32_f16(A, Bf, C, 0, 0, 0)

// ---------------- weight prep: fp16, transposed, [3*H][KTOT] ----------------
// Wt[(g*H + j)][k] = (k < H) ? W_g[k][j] : U_g[k-H][j]
__global__ void prep_weights(const float* __restrict__ Wr, const float* __restrict__ Wc,
                             const float* __restrict__ Wo, const float* __restrict__ Ur,
                             const float* __restrict__ Uc, const float* __restrict__ Uo,
                             _Float16* __restrict__ Wt) {
    int b  = blockIdx.x;            // 0..191
    int g  = b >> 6;                // gate 0..2
    int j0 = (b & 63) << 4;         // 16 columns per block
    const float* W = (g == 0) ? Wr : (g == 1) ? Wc : Wo;
    const float* U = (g == 0) ? Ur : (g == 1) ? Uc : Uo;
    int jj = threadIdx.x & 15;
    int kk = threadIdx.x >> 4;      // 0..15
    for (int k0 = 0; k0 < KTOT; k0 += 16) {
        int k = k0 + kk;
        float v = (k < H_) ? W[(size_t)k * H_ + j0 + jj]
                           : U[(size_t)(k - H_) * H_ + j0 + jj];
        Wt[(size_t)(g * H_ + j0 + jj) * KTOT + k] = (_Float16)v;
    }
}

// ---------------- persistent counter-sync recurrence kernel ----------------
// FINAL (best of 15 variants, verified 1812 us / 3.54 us/step):
// 256 blocks x 512 threads (8 waves). group = bid>>5 (8 batch rows),
// cg = bid&31 (32 h-cols). Wave w K-split: h-k [128w,+128), x-k [64w,+64).
// Weights register-resident. Detection via ONE per-group arrival counter:
//   producer: h fp16 stores sc0sc1 -> vmcnt(0) (ACKed in LLC) -> barrier ->
//             tid0 atomicAdd(cnt[group], 1)   (32 blocks/group/step)
//   consumer: poll cnt[group] (single dword, all lanes same addr) until
//             >= 32*t, then load h data ONCE (sc0sc1, plain fp16, no tags).
// Counter is monotone -> no livelock, no cascade. Triple-buffered h.
// Measured-rejected alternatives: flag-line store (R14, +3%), per-wave flag
// subsets (R15, +34% — wave desync), sleep backoff (R8, +20%), tag-fused
// polls (R4-R11, +44%+), XCD-local exchange (R3, livelock), jitter bundle
// (R13, +7%). Residual per step = LLC RTs + 8MB/step all-to-all h-read +
// straggler-max over 32 producers — structure is at its measured floor.
__global__ __launch_bounds__(NTHR, 2)
void plstm_cnt(const float* __restrict__ x,
               const float* __restrict__ ts,
               const float* __restrict__ br,
               const float* __restrict__ bc,
               const float* __restrict__ bo,
               const _Float16* __restrict__ Wt,
               _Float16* __restrict__ hbuf,     // [3][64][1024] fp16
               unsigned* __restrict__ cnt,      // [8] counters, 128B apart
               float* __restrict__ out) {
    __shared__ float    red[8 * 768];       // [wave][gate][8*32] = 24 KB
    __shared__ _Float16 hlog[64 * 256];     // 64-deep h log      = 32 KB

    const int tid = threadIdx.x;
    const int bid = blockIdx.x;
    const int grp = bid >> 5;            // batch-row group 0..7
    const int cg  = bid & 31;            // h-col group 0..31
    const int r0  = grp << 3;            // 8 rows
    const int c0  = cg << 5;             // 32 cols

    const int lane = tid & 63;
    const int w    = tid >> 6;           // wave 0..7
    const int arow = r0 + (lane & 7);    // A rows (M=8; lanes 8-15 duplicate)
    const int kblk = lane >> 4;          // 0..3
    const int jcol = lane & 15;          // B-fragment column within 16-col tile

    // ---- ALL weights into registers (AGPR-resident on gfx950) ----
    f16x8 bfh[3][2][4], bfx[3][2][2];
    #pragma unroll
    for (int g3 = 0; g3 < 3; ++g3)
        #pragma unroll
        for (int ct = 0; ct < 2; ++ct) {
            const _Float16* base = Wt + (size_t)(g3 * H_ + c0 + ct * 16 + jcol) * KTOT;
            #pragma unroll
            for (int sub = 0; sub < 4; ++sub)
                bfh[g3][ct][sub] = *(const f16x8*)(base + w * 128 + sub * 32 + kblk * 8);
            #pragma unroll
            for (int sub = 0; sub < 2; ++sub)
                bfx[g3][ct][sub] = *(const f16x8*)(base + H_ + w * 64 + sub * 32 + kblk * 8);
        }

    const int erow = tid >> 5;           // owner mapping (tid<256): 8 rows x 32 cols
    const int ecol = tid & 31;
    const int gb   = r0 + (erow & 7);
    const int gh   = c0 + ecol;
    float biasr = 0.f, biasc = 0.f, biaso = 0.f;
    if (tid < 256) { biasr = br[gh]; biasc = bc[gh]; biaso = bo[gh]; }
    float cst = 0.f, kst = 0.f, hval = 0.f;

    const unsigned* const cp = cnt + grp * 32;   // this group's counter (128B line)

    // ---- priming: x(0), ts(0) via plain loads (compiler-managed waits) ----
    f32x4 xn0, xn1, xn2, xn3; float tvn = 0.f;
    {
        const float* xp = x + (size_t)arow * S_ * F_ + w * 64 + kblk * 8;
        xn0 = *(const f32x4*)xp;        xn1 = *(const f32x4*)(xp + 4);
        xn2 = *(const f32x4*)(xp + 32); xn3 = *(const f32x4*)(xp + 36);
        if (tid < 256) tvn = ts[(size_t)gb * S_];
        else if (w < 4) tvn = 0.f;
    }
    f16x8 xf0, xf1;
    #pragma unroll
    for (int r = 0; r < 4; ++r) { xf0[r] = (_Float16)xn0[r]; xf0[4 + r] = (_Float16)xn1[r]; }
    #pragma unroll
    for (int r = 0; r < 4; ++r) { xf1[r] = (_Float16)xn2[r]; xf1[4 + r] = (_Float16)xn3[r]; }
    float tv = tvn;

    for (int t = 0; t < S_; ++t) {
        // ---- x-part MFMAs (pure reg) overlap the counter round trip ----
        f32x4 acc[3][2] = {};
        #pragma unroll
        for (int g3 = 0; g3 < 3; ++g3)
            #pragma unroll
            for (int ct = 0; ct < 2; ++ct) {
                acc[g3][ct] = MFMA16(xf0, bfx[g3][ct][0], acc[g3][ct]);
                acc[g3][ct] = MFMA16(xf1, bfx[g3][ct][1], acc[g3][ct]);
            }

        // ---- detect: poll ONE dword until all 32 group blocks arrived ----
        if (t > 0) {
            const unsigned tgt = 32u * (unsigned)t;
            unsigned c;
            for (unsigned it = 0; it < (1u << 17); ++it) {
                asm volatile("global_load_dword %0, %1, off sc0 sc1\n\t"
                             "s_waitcnt vmcnt(0)"
                             : "=v"(c) : "v"(cp) : "memory");
                if (c >= tgt) break;   // same addr across lanes -> uniform
            }
        }
        __builtin_amdgcn_sched_barrier(0);

        // ---- h data loads: ONCE, plain fp16, guaranteed fresh ----
        const _Float16* hb = hbuf + (size_t)(t % 3) * B_ * H_
                                  + (size_t)arow * H_ + w * 128 + kblk * 8;
        f16x8 hfr[4];
        #pragma unroll
        for (int s = 0; s < 4; ++s)
            asm volatile("global_load_dwordx4 %0, %1, off sc0 sc1"
                         : "=v"(hfr[s]) : "v"(hb + s * 32));
        asm volatile("s_waitcnt vmcnt(0)" ::: "memory");
        __builtin_amdgcn_sched_barrier(0);

        // ---- prefetch x, ts for t+1 (plain loads, hidden under h-MFMAs) ----
        if (t + 1 < S_) {
            const float* xp = x + ((size_t)arow * S_ + (t + 1)) * F_ + w * 64 + kblk * 8;
            xn0 = *(const f32x4*)xp;        xn1 = *(const f32x4*)(xp + 4);
            xn2 = *(const f32x4*)(xp + 32); xn3 = *(const f32x4*)(xp + 36);
            if (tid < 256) tvn = ts[(size_t)gb * S_ + t + 1];
        }

        // ---- h-part MFMAs (pure reg) ----
        #pragma unroll
        for (int s = 0; s < 4; ++s)
            #pragma unroll
            for (int g3 = 0; g3 < 3; ++g3) {
                acc[g3][0] = MFMA16(hfr[s], bfh[g3][0][s], acc[g3][0]);
                acc[g3][1] = MFMA16(hfr[s], bfh[g3][1][s], acc[g3][1]);
            }

        // ---- cross-wave reduce: explicit per-wave slots ----
        if (lane < 32) {
            float* rw = red + w * 768;
            const int crow = (lane >> 4) << 2;
            const int ccol = lane & 15;
            #pragma unroll
            for (int i = 0; i < 4; ++i) {
                const int rr = (crow + i) * 32 + ccol;
                rw[rr]              = acc[0][0][i];  rw[rr + 16]         = acc[0][1][i];
                rw[256 + rr]        = acc[1][0][i];  rw[256 + rr + 16]   = acc[1][1][i];
                rw[512 + rr]        = acc[2][0][i];  rw[512 + rr + 16]   = acc[2][1][i];
            }
        }
        __syncthreads();   // barrier #1: red ready

        // ---- owners: sum partials ----
        float pr = biasr, pc = biasc, po = biaso;
        if (tid < 256) {
            #pragma unroll
            for (int ww = 0; ww < 8; ++ww) {
                pr += red[ww * 768 + tid];
                pc += red[ww * 768 + 256 + tid];
                po += red[ww * 768 + 512 + tid];
            }
        }

        if (tid < 256) {
            // ---- elementwise pLSTM update (f32) ----
            const float r = 1.f / (1.f + __expf(-pr));
            kst = r * tv + (1.f - r) * kst;
            const float e2 = __expf(2.f * pc);
            const float ctil = (e2 - 1.f) / (e2 + 1.f);
            const float d = tv - kst;
            const float f = __fsqrt_rn((d + EPS_) / (d + 1.f));  // ((d+1)/(d+eps))^-0.5
            cst = f * cst + (1.f - f) * ctil;
            const float o = 1.f / (1.f + __expf(-po));
            const float e2c = __expf(2.f * cst);
            hval = o * ((e2c - 1.f) / (e2c + 1.f));

            // publish plain fp16 h for t+1 (sc0sc1 -> LLC)
            if (t + 1 < S_) {
                union { _Float16 hf; unsigned short us; } cv; cv.hf = (_Float16)hval;
                unsigned short* hp = (unsigned short*)(hbuf
                    + (size_t)((t + 1) % 3) * B_ * H_ + (size_t)gb * H_ + gh);
                unsigned uv = cv.us;
                asm volatile("global_store_short %0, %1, off sc0 sc1"
                             :: "v"(hp), "v"(uv) : "memory");
            }
            hlog[(t & 63) * 256 + tid] = (_Float16)hval;
        }

        // ---- ACK publishes, then arrive: one atomic per block ----
        asm volatile("s_waitcnt vmcnt(0)" ::: "memory");  // owner stores ACKed in LLC
        __syncthreads();   // barrier #2: all owner waves' publishes ACKed; red free
        if (tid == 0 && t + 1 < S_)
            __hip_atomic_fetch_add((unsigned*)cp, 1u,
                                   __ATOMIC_RELAXED, __HIP_MEMORY_SCOPE_AGENT);

        // ---- non-owners: burst-flush hlog every 32 steps (off critical path,
        //      overlapped with next step's x-MFMA + poll) ----
        if (tid >= 256 && (t & 31) == 0 && t) {
            const int tbase = t - 32;
            #pragma unroll
            for (int p = 0; p < 4; ++p) {
                const int m  = p * 256 + (tid - 256);  // 0..1023 chunks of 8 fp16
                const int dt = m >> 5;                 // 0..31
                const int c  = m & 31;                 // chunk within step
                f16x8 v = *(const f16x8*)(hlog + ((tbase + dt) & 63) * 256 + c * 8);
                float* op = out + ((size_t)(r0 + (c >> 2)) * S_ + tbase + dt) * H_
                                + c0 + (c & 3) * 8;
                f32x4 o0, o1;
                #pragma unroll
                for (int r2 = 0; r2 < 4; ++r2) { o0[r2] = (float)v[r2]; o1[r2] = (float)v[4 + r2]; }
                *(f32x4*)op = o0;
                *(f32x4*)(op + 4) = o1;
            }
        }

        // ---- tail: convert prefetched x ----
        if (t + 1 < S_) {
            #pragma unroll
            for (int r2 = 0; r2 < 4; ++r2) { xf0[r2] = (_Float16)xn0[r2]; xf0[4 + r2] = (_Float16)xn1[r2]; }
            #pragma unroll
            for (int r2 = 0; r2 < 4; ++r2) { xf1[r2] = (_Float16)xn2[r2]; xf1[4 + r2] = (_Float16)xn3[r2]; }
            tv = tvn;
        }
    }

    // ---- final flush of last 32 steps + final states ----
    __syncthreads();
    {
        const int tbase = S_ - 32;
        #pragma unroll
        for (int p = 0; p < 2; ++p) {
            const int m  = p * 512 + tid;
            const int dt = m >> 5;
            const int c  = m & 31;
            f16x8 v = *(const f16x8*)(hlog + ((tbase + dt) & 63) * 256 + c * 8);
            float* op = out + ((size_t)(r0 + (c >> 2)) * S_ + tbase + dt) * H_
                            + c0 + (c & 3) * 8;
            f32x4 o0, o1;
            #pragma unroll
            for (int r2 = 0; r2 < 4; ++r2) { o0[r2] = (float)v[r2]; o1[r2] = (float)v[4 + r2]; }
            *(f32x4*)op = o0;
            *(f32x4*)(op + 4) = o1;
        }
    }
    if (tid < 256) {
        const size_t BSH = (size_t)B_ * S_ * H_;
        out[BSH +                       (size_t)gb * H_ + gh] = hval;  // h_T
        out[BSH + (size_t)B_ * H_ +     (size_t)gb * H_ + gh] = cst;   // c_T
        out[BSH + 2 * (size_t)B_ * H_ + (size_t)gb * H_ + gh] = kst;   // k_T
    }
}

extern "C" void kernel_launch(void* const* d_in, const int* in_sizes, int n_in,
                              void* d_out, int out_size, void* d_ws, size_t ws_size,
                              hipStream_t stream) {
    (void)in_sizes; (void)n_in; (void)out_size; (void)ws_size;
    const float* x  = (const float*)d_in[0];
    const float* ts = (const float*)d_in[1];
    const float* Ur = (const float*)d_in[2];
    const float* Wr = (const float*)d_in[3];
    const float* br = (const float*)d_in[4];
    const float* Uc = (const float*)d_in[5];
    const float* Wc = (const float*)d_in[6];
    const float* bc = (const float*)d_in[7];
    const float* Uo = (const float*)d_in[8];
    const float* Wo = (const float*)d_in[9];
    const float* bo = (const float*)d_in[10];
    float* out = (float*)d_out;

    char* ws = (char*)d_ws;
    unsigned*  cnt  = (unsigned*)(ws + WS_CNT_OFF);
    _Float16*  hbuf = (_Float16*)(ws + WS_HBUF_OFF);
    _Float16*  Wt   = (_Float16*)(ws + WS_WT_OFF);

    // zero counters + ALL h slots every launch (monotone counters must restart
    // at 0 for graph replay; h slot 0 zero = valid h_0).
    hipMemsetAsync(ws, 0, WS_HBUF_OFF + 3 * B_ * H_ * 2, stream);

    prep_weights<<<192, 256, 0, stream>>>(Wr, Wc, Wo, Ur, Uc, Uo, Wt);

    plstm_cnt<<<NBLK, NTHR, 0, stream>>>(x, ts, br, bc, bo, Wt, hbuf, cnt, out);
}